// Round 12
// baseline (820.116 us; speedup 1.0000x reference)
//
#include <hip/hip_runtime.h>
#include <math.h>

constexpr int N = 50000;     // nodes
constexpr int E = 100000;    // edges
constexpr int B = 256;       // graphs
constexpr int H = 64;
constexpr int DN = 110;

#define DEV __device__ __forceinline__

typedef __attribute__((ext_vector_type(8))) short short8;
typedef __attribute__((ext_vector_type(4))) float floatx4;

DEV float sigf(float x) { return 1.0f / (1.0f + expf(-x)); }

// bf16 round-to-nearest-even conversion (manual, header-type-free)
DEV short f2bf(float f) {
    unsigned u = __float_as_uint(f);
    unsigned r = (u + 0x7fffu + ((u >> 16) & 1u)) >> 16;
    return (short)r;
}
DEV float bf2f(short s) { return __uint_as_float(((unsigned)(unsigned short)s) << 16); }

// convert 8 contiguous floats -> hi/lo bf16 fragments
DEV void cvt8(const float* p, short8& hi, short8& lo) {
    float4 u0 = *(const float4*)p;
    float4 u1 = *(const float4*)(p + 4);
    float vv[8] = {u0.x, u0.y, u0.z, u0.w, u1.x, u1.y, u1.z, u1.w};
#pragma unroll
    for (int j = 0; j < 8; ++j) {
        short hb = f2bf(vv[j]);
        hi[j] = hb;
        lo[j] = f2bf(vv[j] - bf2f(hb));
    }
}

// ---------------- generic helpers ----------------
__global__ void k_izero(int* p, int n) {
    int i = blockIdx.x * 256 + threadIdx.x;
    if (i < n) p[i] = 0;
}

// ---------------- fused prep device helpers ----------------
DEV void d_transpose(const float* in, float* out, int R, int C, int idx) {
    int r = idx / C, c = idx % C;
    out[c * R + r] = in[idx];
}

DEV void d_prepB(const float* __restrict__ W, short* __restrict__ out,
                 int NT16, int ld, int trans, int ocap, int idx) {
    int lane = idx & 63;
    int t = idx >> 6;
    int ntile = t % NT16;
    int kt = t / NT16;
    int quad = lane >> 4, col = lane & 15;
    int o = ntile * 16 + col;
    short hi[8], lo[8];
#pragma unroll
    for (int j = 0; j < 8; ++j) {
        int k = kt * 32 + quad * 8 + j;
        float v = 0.0f;
        if (o < ocap) v = trans ? W[(size_t)o * ld + k] : W[(size_t)k * ld + o];
        short hb = f2bf(v);
        hi[j] = hb;
        lo[j] = f2bf(v - bf2f(hb));
    }
    short* dh = out + (((size_t)(t * 2 + 0) * 64 + lane) * 8);
    short* dl = out + (((size_t)(t * 2 + 1) * 64 + lane) * 8);
#pragma unroll
    for (int j = 0; j < 8; ++j) { dh[j] = hi[j]; dl[j] = lo[j]; }
}

DEV void d_prepW(const float* __restrict__ bond_W, const float* __restrict__ bond_b,
                 short* __restrict__ wf, int idx) {
    int lane = idx & 63;
    int t = idx >> 6;            // (kk*4+nt)*2+ks
    int ks = t & 1;
    int nt = (t >> 1) & 3;
    int kk = t >> 3;
    const float* S = (kk < 16) ? (bond_W + kk * 4096) : bond_b;
    int quad = lane >> 4, col = lane & 15;
    short hi[8], lo[8];
#pragma unroll
    for (int j = 0; j < 8; ++j) {
        int i = ks * 32 + quad * 8 + j;
        float v = S[i * 64 + nt * 16 + col];
        short hb = f2bf(v);
        hi[j] = hb;
        lo[j] = f2bf(v - bf2f(hb));
    }
    short* dh = wf + (((size_t)(t * 2 + 0) * 64 + lane) * 8);
    short* dl = wf + (((size_t)(t * 2 + 1) * 64 + lane) * 8);
#pragma unroll
    for (int j = 0; j < 8; ++j) { dh[j] = hi[j]; dl[j] = lo[j]; }
}

// fused start-of-graph prep: 4 LSTM transposes + bond prepW + 2 gru prepB + state zero
__launch_bounds__(256)
__global__ void k_prep0(const float* lWih0, const float* lWhh0, const float* lWih1, const float* lWhh1,
                        float* lW0T, float* lU0T, float* lW1T, float* lU1T,
                        const float* bond_W, const float* bond_b, short* wf,
                        const float* gru_Wih, const float* gru_Whh, short* fgI, short* fgH,
                        float* zreg) {
    int idx = blockIdx.x * 256 + threadIdx.x;
    if (idx < 131072) { d_transpose(lWih0, lW0T, 512, 256, idx); return; }
    idx -= 131072;
    if (idx < 65536) { d_transpose(lWhh0, lU0T, 512, 128, idx); return; }
    idx -= 65536;
    if (idx < 65536) { d_transpose(lWih1, lW1T, 512, 128, idx); return; }
    idx -= 65536;
    if (idx < 65536) { d_transpose(lWhh1, lU1T, 512, 128, idx); return; }
    idx -= 65536;
    if (idx < 8704) { d_prepW(bond_W, bond_b, wf, idx); return; }
    idx -= 8704;
    if (idx < 1536) { d_prepB(gru_Wih, fgI, 12, 64, 1, 192, idx); return; }
    idx -= 1536;
    if (idx < 1536) { d_prepB(gru_Whh, fgH, 12, 64, 1, 192, idx); return; }
    idx -= 1536;
    if (idx < 196608) { zreg[idx] = 0.0f; return; }
}
constexpr int PREP0_TOTAL = 131072 + 3 * 65536 + 8704 + 2 * 1536 + 196608;

// fused head prep: 4 prepB jobs (runs after MP loop; buffers alias ef_t)
__launch_bounds__(256)
__global__ void k_prephead(const float* sp_W, short* fsp, const float* h0_W1, short* fw1,
                           const float* h0_W2, short* fw2, const float* out_W, short* fow) {
    int idx = blockIdx.x * 256 + threadIdx.x;
    if (idx < 16384) { d_prepB(sp_W, fsp, 32, 512, 0, 512, idx); return; }
    idx -= 16384;
    if (idx < 32768) { d_prepB(h0_W1, fw1, 32, 512, 0, 512, idx); return; }
    idx -= 32768;
    if (idx < 32768) { d_prepB(h0_W2, fw2, 32, 512, 0, 512, idx); return; }
    idx -= 32768;
    if (idx < 4096) { d_prepB(out_W, fow, 4, 54, 0, 54, idx); return; }
}
constexpr int PREPH_TOTAL = 16384 + 2 * 32768 + 4096;

// ---------------- edge sort by dst (counting sort), one-time ----------------
__global__ void k_deg(const int* __restrict__ dst, int* __restrict__ deg) {
    int e = blockIdx.x * 256 + threadIdx.x;
    if (e < E) atomicAdd(&deg[dst[e]], 1);
}
__global__ void k_scan1(const int* __restrict__ deg, int* __restrict__ bsum) {
    __shared__ int s[256];
    int b = blockIdx.x, tid = threadIdx.x;
    int idx = b * 256 + tid;
    s[tid] = (idx < N) ? deg[idx] : 0;
    __syncthreads();
    for (int st = 128; st > 0; st >>= 1) {
        if (tid < st) s[tid] += s[tid + st];
        __syncthreads();
    }
    if (tid == 0) bsum[b] = s[0];
}
__global__ void k_scan2p(int* __restrict__ bsum, int nb) {
    __shared__ int s[256];
    int tid = threadIdx.x;
    int v = (tid < nb) ? bsum[tid] : 0;
    s[tid] = v;
    __syncthreads();
    for (int off = 1; off < 256; off <<= 1) {
        int t = (tid >= off) ? s[tid - off] : 0;
        __syncthreads();
        s[tid] += t;
        __syncthreads();
    }
    if (tid < nb) bsum[tid] = s[tid] - v;   // exclusive
}
__global__ void k_scan3(const int* __restrict__ deg, const int* __restrict__ bsum,
                        int* __restrict__ cursor, int* __restrict__ roff) {
    __shared__ int s[256];
    int b = blockIdx.x, tid = threadIdx.x;
    int idx = b * 256 + tid;
    int v = (idx < N) ? deg[idx] : 0;
    s[tid] = v;
    __syncthreads();
    for (int off = 1; off < 256; off <<= 1) {
        int t = (tid >= off) ? s[tid - off] : 0;
        __syncthreads();
        s[tid] += t;
        __syncthreads();
    }
    if (idx < N) {
        int start = bsum[b] + s[tid] - v;
        cursor[idx] = start;
        roff[idx] = start;
    }
    if (idx == 0) roff[N] = E;
}
__global__ void k_scat(const int* __restrict__ src, const int* __restrict__ dst,
                       int* __restrict__ cursor, int* __restrict__ srcp,
                       int* __restrict__ epos) {
    int e = blockIdx.x * 256 + threadIdx.x;
    if (e >= E) return;
    int d = dst[e];
    int pos = atomicAdd(&cursor[d], 1);
    srcp[pos] = src[e];
    epos[e] = pos;
}

// ---------------- projection: v = relu(na @ W + b); x = v (fp32); hs = split(v) ----------------
__launch_bounds__(256)
__global__ void k_proj(const float* __restrict__ na, const float* __restrict__ W,
                       const float* __restrict__ b, float* __restrict__ x,
                       short* __restrict__ hs) {
    __shared__ float Ws[DN * 64];
    __shared__ float as[16][112];
    int tid = threadIdx.x;
    for (int i = tid; i < DN * 64; i += 256) Ws[i] = W[i];
    int n0 = blockIdx.x * 16;
    for (int i = tid; i < 16 * DN; i += 256) {
        int nn = i / DN, ii = i % DN;
        as[nn][ii] = na[(n0 + nn) * DN + ii];
    }
    __syncthreads();
    int o = tid & 63, ng = tid >> 6;
    float bo = b[o];
    for (int j = 0; j < 4; ++j) {
        int nn = ng * 4 + j;
        float acc = bo;
#pragma unroll 10
        for (int i = 0; i < DN; ++i) acc += as[nn][i] * Ws[i * 64 + o];
        float v = fmaxf(acc, 0.0f);
        int n = n0 + nn;
        x[(size_t)n * 64 + o] = v;
        short hb = f2bf(v);
        hs[(size_t)n * 128 + o] = hb;
        hs[(size_t)n * 128 + 64 + o] = f2bf(v - bf2f(hb));
    }
}

// ---------------- edge features -> ef_t[kk][pos] in dst-sorted order ----------------
__global__ void k_efeat2(const float* __restrict__ ea, const float* __restrict__ el,
                         const float* __restrict__ centers, const float* __restrict__ beta,
                         const int* __restrict__ epos, float* __restrict__ ef_t) {
    int e = blockIdx.x * 256 + threadIdx.x;
    if (e >= E) return;
    int pos = epos[e];
    float L = el[e];
#pragma unroll
    for (int j = 0; j < 8; ++j) ef_t[j * E + pos] = ea[e * 8 + j];
#pragma unroll
    for (int j = 0; j < 8; ++j) {
        float d = L - centers[j];
        ef_t[(8 + j) * E + pos] = expf(-beta[j] * d * d);
    }
    ef_t[16 * E + pos] = 1.0f;
}

// ---------------- message GEMM, M=64, 2-deep B prefetch, non-temporal streams ----------------
__launch_bounds__(256)
__global__ void k_msg7(const short* __restrict__ hs, const float* __restrict__ ef_t,
                       const short* __restrict__ wf, const int* __restrict__ srcp,
                       float* __restrict__ m) {
    __shared__ float efs[17 * 64];   // [kk][e_local]
    __shared__ int srcs[64];

    int tid = threadIdx.x;
    int e0 = blockIdx.x * 64;
    int lane = tid & 63;
    int nt = tid >> 6;
    int quad = lane >> 4, col = lane & 15;

    if (tid < 64) {
        int eg = e0 + tid;
        srcs[tid] = (eg < E) ? srcp[eg] : 0;
    }
    for (int i = tid; i < 17 * 64; i += 256) {
        int kk = i >> 6, e = i & 63;
        int eg = e0 + e;
        efs[i] = (eg < E) ? __builtin_nontemporal_load(ef_t + (size_t)kk * E + eg) : 0.0f;
    }
    __syncthreads();

    // A fragments: direct pre-split loads (hi at +0..63, lo at +64..127 per node row)
    short8 Ah[4][2], Al[4][2];
#pragma unroll
    for (int mt = 0; mt < 4; ++mt) {
        int s = srcs[mt * 16 + col];
        const short* hp = hs + (size_t)s * 128 + quad * 8;
#pragma unroll
        for (int ks = 0; ks < 2; ++ks) {
            Ah[mt][ks] = *(const short8*)(hp + ks * 32);
            Al[mt][ks] = *(const short8*)(hp + 64 + ks * 32);
        }
    }

    const short8* Wf = (const short8*)wf;
    float C[4][4] = {};

#define LOADB(d0, d1, d2, d3, KK)                      \
    {                                                  \
        int tb_ = ((KK) * 4 + nt) * 2;                 \
        d0 = Wf[((tb_ + 0) * 2 + 0) * 64 + lane];      \
        d1 = Wf[((tb_ + 1) * 2 + 0) * 64 + lane];      \
        d2 = Wf[((tb_ + 0) * 2 + 1) * 64 + lane];      \
        d3 = Wf[((tb_ + 1) * 2 + 1) * 64 + lane];      \
    }

    // 2-deep software pipeline: cur = kk, nxt = kk+1; prefetch kk+2 each iteration
    short8 c0, c1, c2, c3, n0, n1, n2, n3;
    LOADB(c0, c1, c2, c3, 0);
    LOADB(n0, n1, n2, n3, 1);

#pragma unroll 1
    for (int kk = 0; kk < 17; ++kk) {
        int kn = kk + 2;
        if (kn > 16) kn = 16;
        short8 p0, p1, p2, p3;
        LOADB(p0, p1, p2, p3, kn);

#pragma unroll
        for (int mt = 0; mt < 4; ++mt) {
            floatx4 T = {0.0f, 0.0f, 0.0f, 0.0f};
            T = __builtin_amdgcn_mfma_f32_16x16x32_bf16(Ah[mt][0], c0, T, 0, 0, 0);
            T = __builtin_amdgcn_mfma_f32_16x16x32_bf16(Ah[mt][1], c1, T, 0, 0, 0);
            T = __builtin_amdgcn_mfma_f32_16x16x32_bf16(Al[mt][0], c0, T, 0, 0, 0);
            T = __builtin_amdgcn_mfma_f32_16x16x32_bf16(Al[mt][1], c1, T, 0, 0, 0);
            T = __builtin_amdgcn_mfma_f32_16x16x32_bf16(Ah[mt][0], c2, T, 0, 0, 0);
            T = __builtin_amdgcn_mfma_f32_16x16x32_bf16(Ah[mt][1], c3, T, 0, 0, 0);
            float4 ef = *(const float4*)&efs[kk * 64 + mt * 16 + quad * 4];
            C[mt][0] += ef.x * T[0];
            C[mt][1] += ef.y * T[1];
            C[mt][2] += ef.z * T[2];
            C[mt][3] += ef.w * T[3];
        }
        c0 = n0; c1 = n1; c2 = n2; c3 = n3;
        n0 = p0; n1 = p1; n2 = p2; n3 = p3;
    }
#undef LOADB

    // epilogue: non-temporal plain stores (write-once stream; keep wfrag/hs hot in L2)
    int o = nt * 16 + col;
#pragma unroll
    for (int mt = 0; mt < 4; ++mt) {
#pragma unroll
        for (int r = 0; r < 4; ++r) {
            int eg = e0 + mt * 16 + quad * 4 + r;
            if (eg < E) __builtin_nontemporal_store(C[mt][r], m + (size_t)eg * 64 + o);
        }
    }
}

// ---------------- GRU step: CSR gather + conv_b + relu -> split-bf16 MFMA; h stored split in hs ----------------
__launch_bounds__(256)
__global__ void k_gru3(const float* __restrict__ m, const int* __restrict__ roff,
                       const float* __restrict__ conv_b, short* __restrict__ hs,
                       const short* __restrict__ fI, const short* __restrict__ fH,
                       const float* __restrict__ bih, const float* __restrict__ bhh) {
    int tid = threadIdx.x, lane = tid & 63, nt = tid >> 6;
    int quad = lane >> 4, col = lane & 15;
    int n0 = blockIdx.x * 32;

    short8 Gh[2][2], Gl[2][2], Hh[2][2], Hl[2][2];
#pragma unroll
    for (int mt = 0; mt < 2; ++mt) {
        int node = n0 + mt * 16 + col;
        bool ok = node < N;
        int nc = ok ? node : (N - 1);
        int rs = roff[nc];
        int re = ok ? roff[nc + 1] : rs;
        float acc[2][8];
#pragma unroll
        for (int ks = 0; ks < 2; ++ks) {
            const float* cb = conv_b + ks * 32 + quad * 8;
#pragma unroll
            for (int j = 0; j < 8; ++j) acc[ks][j] = cb[j];
        }
        for (int r = rs; r < re; ++r) {
            const float* mp = m + (size_t)r * 64 + quad * 8;
            floatx4 a0 = __builtin_nontemporal_load((const floatx4*)mp);
            floatx4 a1 = __builtin_nontemporal_load((const floatx4*)(mp + 4));
            floatx4 b0 = __builtin_nontemporal_load((const floatx4*)(mp + 32));
            floatx4 b1 = __builtin_nontemporal_load((const floatx4*)(mp + 36));
            acc[0][0] += a0[0]; acc[0][1] += a0[1]; acc[0][2] += a0[2]; acc[0][3] += a0[3];
            acc[0][4] += a1[0]; acc[0][5] += a1[1]; acc[0][6] += a1[2]; acc[0][7] += a1[3];
            acc[1][0] += b0[0]; acc[1][1] += b0[1]; acc[1][2] += b0[2]; acc[1][3] += b0[3];
            acc[1][4] += b1[0]; acc[1][5] += b1[1]; acc[1][6] += b1[2]; acc[1][7] += b1[3];
        }
        const short* hp = hs + (size_t)nc * 128 + quad * 8;
#pragma unroll
        for (int ks = 0; ks < 2; ++ks) {
            short8 hh8 = *(const short8*)(hp + ks * 32);
            short8 hl8 = *(const short8*)(hp + 64 + ks * 32);
            Hh[mt][ks] = hh8;
            Hl[mt][ks] = hl8;
#pragma unroll
            for (int j = 0; j < 8; ++j) {
                float g = ok ? fmaxf(acc[ks][j], 0.0f) : 0.0f;
                short gb = f2bf(g);
                Gh[mt][ks][j] = gb;
                Gl[mt][ks][j] = f2bf(g - bf2f(gb));
            }
        }
        if (!ok) {
#pragma unroll
            for (int ks = 0; ks < 2; ++ks) {
                Hh[mt][ks] = short8{0,0,0,0,0,0,0,0};
                Hl[mt][ks] = short8{0,0,0,0,0,0,0,0};
            }
        }
    }
    __syncthreads();  // all hs reads complete before any wave writes hs below

    const short8* FI = (const short8*)fI;
    const short8* FH = (const short8*)fH;
    floatx4 aI[2][3] = {}, aH[2][3] = {};
#pragma unroll
    for (int ks = 0; ks < 2; ++ks) {
        short8 bIh[3], bIl[3], bHh[3], bHl[3];
#pragma unroll
        for (int g = 0; g < 3; ++g) {
            int t = ks * 12 + g * 4 + nt;   // NT16 = 12 (Nout=192)
            bIh[g] = FI[(t * 2 + 0) * 64 + lane];
            bIl[g] = FI[(t * 2 + 1) * 64 + lane];
            bHh[g] = FH[(t * 2 + 0) * 64 + lane];
            bHl[g] = FH[(t * 2 + 1) * 64 + lane];
        }
#pragma unroll
        for (int mt = 0; mt < 2; ++mt) {
#pragma unroll
            for (int g = 0; g < 3; ++g) {
                aI[mt][g] = __builtin_amdgcn_mfma_f32_16x16x32_bf16(Gh[mt][ks], bIh[g], aI[mt][g], 0, 0, 0);
                aI[mt][g] = __builtin_amdgcn_mfma_f32_16x16x32_bf16(Gl[mt][ks], bIh[g], aI[mt][g], 0, 0, 0);
                aI[mt][g] = __builtin_amdgcn_mfma_f32_16x16x32_bf16(Gh[mt][ks], bIl[g], aI[mt][g], 0, 0, 0);
                aH[mt][g] = __builtin_amdgcn_mfma_f32_16x16x32_bf16(Hh[mt][ks], bHh[g], aH[mt][g], 0, 0, 0);
                aH[mt][g] = __builtin_amdgcn_mfma_f32_16x16x32_bf16(Hl[mt][ks], bHh[g], aH[mt][g], 0, 0, 0);
                aH[mt][g] = __builtin_amdgcn_mfma_f32_16x16x32_bf16(Hh[mt][ks], bHl[g], aH[mt][g], 0, 0, 0);
            }
        }
    }

    int o = nt * 16 + col;
    float br = bih[o], bz = bih[64 + o], bn = bih[128 + o];
    float cr = bhh[o], cz = bhh[64 + o], cn = bhh[128 + o];
#pragma unroll
    for (int mt = 0; mt < 2; ++mt) {
#pragma unroll
        for (int r = 0; r < 4; ++r) {
            int node = n0 + mt * 16 + quad * 4 + r;
            if (node >= N) continue;
            float rg = sigf(aI[mt][0][r] + br + aH[mt][0][r] + cr);
            float z  = sigf(aI[mt][1][r] + bz + aH[mt][1][r] + cz);
            float ng = tanhf(aI[mt][2][r] + bn + rg * (aH[mt][2][r] + cn));
            size_t hb_ = (size_t)node * 128 + o;
            float hold = bf2f(hs[hb_]) + bf2f(hs[hb_ + 64]);
            float hn = (1.0f - z) * ng + z * hold;
            short hi = f2bf(hn);
            hs[hb_] = hi;
            hs[hb_ + 64] = f2bf(hn - bf2f(hi));
        }
    }
}

// ---------------- graph bounds: sorted node_graph -> boundary detection, no atomics ----------------
__global__ void k_bounds2(const int* __restrict__ ng, int* __restrict__ gs, int* __restrict__ ge) {
    int n = blockIdx.x * 256 + threadIdx.x;
    if (n >= N) return;
    int g = ng[n];
    int gp = (n == 0) ? -1 : ng[n - 1];
    if (g != gp) {
        gs[g] = n;
        if (n > 0) ge[gp] = n;
        for (int q = gp + 1; q < g; ++q) { gs[q] = 0; ge[q] = 0; }
    }
    if (n == N - 1) {
        ge[g] = N;
        for (int q = g + 1; q < B; ++q) { gs[q] = 0; ge[q] = 0; }
    }
}

// ---------------- fused Set2Set iteration: 2-layer LSTM + online-softmax attention (4x unrolled) ----------------
__launch_bounds__(256)
__global__ void k_s2s(float* __restrict__ h0, float* __restrict__ c0,
                      float* __restrict__ h1, float* __restrict__ c1,
                      float* __restrict__ q_star,
                      const float* __restrict__ W0T, const float* __restrict__ U0T,
                      const float* __restrict__ b0i, const float* __restrict__ b0h,
                      const float* __restrict__ W1T, const float* __restrict__ U1T,
                      const float* __restrict__ b1i, const float* __restrict__ b1h,
                      const short* __restrict__ hs, const float* __restrict__ x,
                      const int* __restrict__ gs, const int* __restrict__ ge) {
    __shared__ float xb[256], hb[128], gb[512], h0n[128], qv[128];
    __shared__ float mrg[4][2][64];
    __shared__ float ml[4][2];
    int g = blockIdx.x, tid = threadIdx.x;
    xb[tid] = q_star[g * 256 + tid];
    if (tid < 128) hb[tid] = h0[g * 128 + tid];
    __syncthreads();
    // ---- LSTM layer 0 ----
    float g0 = b0i[tid] + b0h[tid];
    float g1 = b0i[tid + 256] + b0h[tid + 256];
    for (int i = 0; i < 256; ++i) {
        float xx = xb[i];
        g0 += xx * W0T[i * 512 + tid];
        g1 += xx * W0T[i * 512 + tid + 256];
    }
    for (int i = 0; i < 128; ++i) {
        float hh = hb[i];
        g0 += hh * U0T[i * 512 + tid];
        g1 += hh * U0T[i * 512 + tid + 256];
    }
    gb[tid] = g0; gb[tid + 256] = g1;
    __syncthreads();
    if (tid < 128) {
        float ii = gb[tid], ff = gb[128 + tid], gg = gb[256 + tid], oo = gb[384 + tid];
        float c = sigf(ff) * c0[g * 128 + tid] + sigf(ii) * tanhf(gg);
        float hn = sigf(oo) * tanhf(c);
        c0[g * 128 + tid] = c; h0[g * 128 + tid] = hn; h0n[tid] = hn;
        hb[tid] = h1[g * 128 + tid];
    }
    __syncthreads();
    // ---- LSTM layer 1 ----
    float ga = b1i[tid] + b1h[tid];
    float gbv = b1i[tid + 256] + b1h[tid + 256];
    for (int i = 0; i < 128; ++i) {
        float xx = h0n[i], hh = hb[i];
        ga  += xx * W1T[i * 512 + tid]       + hh * U1T[i * 512 + tid];
        gbv += xx * W1T[i * 512 + tid + 256] + hh * U1T[i * 512 + tid + 256];
    }
    gb[tid] = ga; gb[tid + 256] = gbv;
    __syncthreads();
    if (tid < 128) {
        float ii = gb[tid], ff = gb[128 + tid], gg = gb[256 + tid], oo = gb[384 + tid];
        float c = sigf(ff) * c1[g * 128 + tid] + sigf(ii) * tanhf(gg);
        float hn = sigf(oo) * tanhf(c);
        c1[g * 128 + tid] = c; h1[g * 128 + tid] = hn;
        q_star[g * 256 + tid] = hn;   // q half
        qv[tid] = hn;
    }
    __syncthreads();
    // ---- attention with online softmax, 4 nodes per iteration (batched loads) ----
    int s0v = gs[g], s1v = ge[g];
    int lane = tid & 63, grp = tid >> 6;
    float qh = qv[lane], qx = qv[64 + lane];
    float mM = -INFINITY, lL = 0.0f, nh = 0.0f, nx = 0.0f;
    for (int n = s0v + grp; n < s1v; n += 16) {
        float hv[4], xv[4], e[4];
#pragma unroll
        for (int j = 0; j < 4; ++j) {
            int nj = n + 4 * j;
            int nc = (nj < s1v) ? nj : n;   // clamp: n itself is always valid
            hv[j] = bf2f(hs[(size_t)nc * 128 + lane]) + bf2f(hs[(size_t)nc * 128 + 64 + lane]);
            xv[j] = x[(size_t)nc * 64 + lane];
            e[j] = hv[j] * qh + xv[j] * qx;
        }
#pragma unroll
        for (int off = 32; off; off >>= 1) {
#pragma unroll
            for (int j = 0; j < 4; ++j) e[j] += __shfl_xor(e[j], off, 64);
        }
#pragma unroll
        for (int j = 0; j < 4; ++j)
            if (n + 4 * j >= s1v) e[j] = -INFINITY;
        float mb = fmaxf(fmaxf(e[0], e[1]), fmaxf(e[2], e[3]));
        float mn = fmaxf(mM, mb);
        float sc = expf(mM - mn);
        float w0 = expf(e[0] - mn), w1 = expf(e[1] - mn);
        float w2 = expf(e[2] - mn), w3 = expf(e[3] - mn);
        lL = lL * sc + ((w0 + w1) + (w2 + w3));
        nh = nh * sc + ((w0 * hv[0] + w1 * hv[1]) + (w2 * hv[2] + w3 * hv[3]));
        nx = nx * sc + ((w0 * xv[0] + w1 * xv[1]) + (w2 * xv[2] + w3 * xv[3]));
        mM = mn;
    }
    mrg[grp][0][lane] = nh;
    mrg[grp][1][lane] = nx;
    if (lane == 0) { ml[grp][0] = mM; ml[grp][1] = lL; }
    __syncthreads();
    if (tid < 128) {
        int half = tid >> 6, dl = tid & 63;
        float M = -INFINITY;
#pragma unroll
        for (int i = 0; i < 4; ++i) M = fmaxf(M, ml[i][0]);
        float L = 0.0f, NUM = 0.0f;
#pragma unroll
        for (int i = 0; i < 4; ++i) {
            float sc = expf(ml[i][0] - M);
            L += ml[i][1] * sc;
            NUM += mrg[i][half][dl] * sc;
        }
        q_star[g * 256 + 128 + tid] = (s1v > s0v) ? NUM / L : 0.0f;
    }
}

// ---------------- head GEMM layer: C = act(A @ W + b), tiled MFMA ----------------
template<int MODE>
__launch_bounds__(256)
__global__ void k_hgemm(const float* __restrict__ A, const short* __restrict__ Bf,
                        const float* __restrict__ bias, const float* __restrict__ pa,
                        float* __restrict__ Cout, int K, int NT16) {
    int tid = threadIdx.x, lane = tid & 63, nt = tid >> 6;
    int quad = lane >> 4, col = lane & 15;
    int s0 = blockIdx.x * 16;
    int ntile = blockIdx.y * 4 + nt;
    int NoutTot = NT16 * 16;
    const short8* F = (const short8*)Bf;
    floatx4 T = {0.0f, 0.0f, 0.0f, 0.0f};
    const float* ap = A + (size_t)(s0 + col) * K + quad * 8;
    int KT = K >> 5;
#pragma unroll 4
    for (int kt = 0; kt < KT; ++kt) {
        short8 ah, al;
        cvt8(ap + kt * 32, ah, al);
        int t = kt * NT16 + ntile;
        short8 bh = F[(t * 2 + 0) * 64 + lane];
        short8 bl = F[(t * 2 + 1) * 64 + lane];
        T = __builtin_amdgcn_mfma_f32_16x16x32_bf16(ah, bh, T, 0, 0, 0);
        T = __builtin_amdgcn_mfma_f32_16x16x32_bf16(al, bh, T, 0, 0, 0);
        T = __builtin_amdgcn_mfma_f32_16x16x32_bf16(ah, bl, T, 0, 0, 0);
    }
    int o = ntile * 16 + col;
    float b = bias[o];
    float a = (MODE == 0) ? pa[0] : 0.0f;
#pragma unroll
    for (int r = 0; r < 4; ++r) {
        float v = T[r] + b;
        if (MODE == 0) v = (v >= 0.0f) ? v : a * v;
        if (MODE == 1) v = fmaxf(v, 0.0f);
        if (MODE == 2) v = tanhf(v);
        Cout[(size_t)(s0 + quad * 4 + r) * NoutTot + o] = v;
    }
}

// ---------------- head output layer + softmax ----------------
__launch_bounds__(256)
__global__ void k_hout(const float* __restrict__ A, const short* __restrict__ Bf,
                       const float* __restrict__ ob, float* __restrict__ out) {
    __shared__ float sm[16][64];
    __shared__ float smax[16], sinv[16];
    int tid = threadIdx.x, lane = tid & 63, nt = tid >> 6;
    int quad = lane >> 4, col = lane & 15;
    int s0 = blockIdx.x * 16;
    const short8* F = (const short8*)Bf;
    floatx4 T = {0.0f, 0.0f, 0.0f, 0.0f};
    const float* ap = A + (size_t)(s0 + col) * 512 + quad * 8;
#pragma unroll 4
    for (int kt = 0; kt < 16; ++kt) {
        short8 ah, al;
        cvt8(ap + kt * 32, ah, al);
        int t = kt * 4 + nt;
        short8 bh = F[(t * 2 + 0) * 64 + lane];
        short8 bl = F[(t * 2 + 1) * 64 + lane];
        T = __builtin_amdgcn_mfma_f32_16x16x32_bf16(ah, bh, T, 0, 0, 0);
        T = __builtin_amdgcn_mfma_f32_16x16x32_bf16(al, bh, T, 0, 0, 0);
        T = __builtin_amdgcn_mfma_f32_16x16x32_bf16(ah, bl, T, 0, 0, 0);
    }
    int o = nt * 16 + col;
    float b = (o < 54) ? ob[o] : 0.0f;
#pragma unroll
    for (int r = 0; r < 4; ++r)
        sm[quad * 4 + r][o] = (o < 54) ? (T[r] + b) : -1e30f;
    __syncthreads();
    if (tid < 16) {
        float m = -INFINITY;
        for (int j = 0; j < 54; ++j) m = fmaxf(m, sm[tid][j]);
        float s = 0.0f;
        for (int j = 0; j < 54; ++j) s += expf(sm[tid][j] - m);
        smax[tid] = m;
        sinv[tid] = 1.0f / s;
    }
    __syncthreads();
    for (int idx = tid; idx < 16 * 54; idx += 256) {
        int srow = idx / 54, oo = idx % 54;
        out[(size_t)(s0 + srow) * 54 + oo] = expf(sm[srow][oo] - smax[srow]) * sinv[srow];
    }
}

// ---------------- driver ----------------
extern "C" void kernel_launch(void* const* d_in, const int* in_sizes, int n_in,
                              void* d_out, int out_size, void* d_ws, size_t ws_size,
                              hipStream_t stream) {
    const float* node_attr = (const float*)d_in[0];
    const float* edge_attr = (const float*)d_in[1];
    const float* edge_len  = (const float*)d_in[2];
    const int*   src       = (const int*)d_in[3];
    const int*   dst       = (const int*)d_in[4];
    const int*   node_grph = (const int*)d_in[5];
    const float* proj_W    = (const float*)d_in[6];
    const float* proj_b    = (const float*)d_in[7];
    const float* centers   = (const float*)d_in[8];
    const float* beta      = (const float*)d_in[9];
    const float* bond_W    = (const float*)d_in[10];
    const float* bond_b    = (const float*)d_in[11];
    const float* conv_b    = (const float*)d_in[12];
    const float* gru_Wih   = (const float*)d_in[13];
    const float* gru_Whh   = (const float*)d_in[14];
    const float* gru_bih   = (const float*)d_in[15];
    const float* gru_bhh   = (const float*)d_in[16];
    const float* lWih0     = (const float*)d_in[17];
    const float* lWhh0     = (const float*)d_in[18];
    const float* lbih0     = (const float*)d_in[19];
    const float* lbhh0     = (const float*)d_in[20];
    const float* lWih1     = (const float*)d_in[21];
    const float* lWhh1     = (const float*)d_in[22];
    const float* lbih1     = (const float*)d_in[23];
    const float* lbhh1     = (const float*)d_in[24];
    const float* sp_W      = (const float*)d_in[25];
    const float* sp_b      = (const float*)d_in[26];
    const float* prelu_a   = (const float*)d_in[27];
    const float* h0_W1     = (const float*)d_in[28];
    const float* h0_b1     = (const float*)d_in[29];
    const float* h0_W2     = (const float*)d_in[30];
    const float* h0_b2     = (const float*)d_in[31];
    const float* out_W     = (const float*)d_in[32];
    const float* out_b     = (const float*)d_in[33];
    float* out = (float*)d_out;

    float* ws = (float*)d_ws;
    size_t off = 0;
    float* x      = ws + off; off += (size_t)N * 64;
    float* hsf    = ws + off; off += (size_t)N * 64;   // N x 128 shorts (hi|lo per node)
    float* ef_t   = ws + off; off += (size_t)E * 17;   // reused by head after MP loop
    float* m      = ws + off; off += (size_t)E * 64;   // per-edge messages (dst-sorted)
    float* wfrag  = ws + off; off += 17 * 16 * 64 * 8 / 2;
    float* fgI    = ws + off; off += 2 * 64 * 192 / 2;
    float* fgH    = ws + off; off += 2 * 64 * 192 / 2;
    float* lW0T   = ws + off; off += 256 * 512;
    float* lU0T   = ws + off; off += 128 * 512;
    float* lW1T   = ws + off; off += 128 * 512;
    float* lU1T   = ws + off; off += 128 * 512;
    float* h0     = ws + off; off += B * 128;
    float* c0     = ws + off; off += B * 128;
    float* h1     = ws + off; off += B * 128;
    float* c1     = ws + off; off += B * 128;
    float* q_star = ws + off; off += B * 256;
    int* gs       = (int*)(ws + off); off += B;
    int* ge       = (int*)(ws + off); off += B;
    int* deg      = (int*)(ws + off); off += N;
    int* cursor   = (int*)(ws + off); off += N;
    int* roff     = (int*)(ws + off); off += N + 1;
    int* bsum     = (int*)(ws + off); off += 256;
    int* srcp     = (int*)(ws + off); off += E;
    int* epos     = (int*)(ws + off); off += E;

    short* hs = (short*)hsf;

    // head buffers alias the ef_t region (dead after the MP loop)
    short* fsp = (short*)ef_t;
    short* fw1 = (short*)(ef_t + 131072);
    short* fw2 = (short*)(ef_t + 131072 + 262144);
    short* fow = (short*)(ef_t + 131072 + 2 * 262144);
    float* hb1 = ef_t + 131072 + 2 * 262144 + 32768;
    float* hb2 = hb1 + 131072;

    constexpr int NB = (N + 255) / 256;   // 196

    // ---- one-time: counting sort of edges by dst + CSR offsets ----
    k_izero<<<NB, 256, 0, stream>>>(deg, N);
    k_deg<<<(E + 255) / 256, 256, 0, stream>>>(dst, deg);
    k_scan1<<<NB, 256, 0, stream>>>(deg, bsum);
    k_scan2p<<<1, 256, 0, stream>>>(bsum, NB);
    k_scan3<<<NB, 256, 0, stream>>>(deg, bsum, cursor, roff);
    k_scat<<<(E + 255) / 256, 256, 0, stream>>>(src, dst, cursor, srcp, epos);

    // fused prep: LSTM transposes + bond/gru fragment prep + LSTM-state zero (h0..q_star contiguous)
    k_prep0<<<(PREP0_TOTAL + 255) / 256, 256, 0, stream>>>(
        lWih0, lWhh0, lWih1, lWhh1, lW0T, lU0T, lW1T, lU1T,
        bond_W, bond_b, (short*)wfrag, gru_Wih, gru_Whh, (short*)fgI, (short*)fgH, h0);

    k_proj<<<N / 16, 256, 0, stream>>>(node_attr, proj_W, proj_b, x, hs);
    k_efeat2<<<(E + 255) / 256, 256, 0, stream>>>(edge_attr, edge_len, centers, beta, epos, ef_t);

    k_bounds2<<<(N + 255) / 256, 256, 0, stream>>>(node_grph, gs, ge);

    for (int step = 0; step < 4; ++step) {
        k_msg7<<<(E + 63) / 64, 256, 0, stream>>>(hs, ef_t, (const short*)wfrag, srcp, m);
        k_gru3<<<(N + 31) / 32, 256, 0, stream>>>(m, roff, conv_b, hs,
                                                  (const short*)fgI, (const short*)fgH,
                                                  gru_bih, gru_bhh);
    }

    // fused head fragment prep (ef_t region now dead)
    k_prephead<<<(PREPH_TOTAL + 255) / 256, 256, 0, stream>>>(
        sp_W, fsp, h0_W1, fw1, h0_W2, fw2, out_W, fow);

    for (int it = 0; it < 3; ++it) {
        k_s2s<<<B, 256, 0, stream>>>(h0, c0, h1, c1, q_star,
                                     lW0T, lU0T, lbih0, lbhh0,
                                     lW1T, lU1T, lbih1, lbhh1,
                                     hs, x, gs, ge);
    }

    // head: 3 MFMA GEMM layers + fused output/softmax
    k_hgemm<0><<<dim3(16, 8), 256, 0, stream>>>(q_star, fsp, sp_b, prelu_a, hb1, 256, 32);
    k_hgemm<1><<<dim3(16, 8), 256, 0, stream>>>(hb1, fw1, h0_b1, nullptr, hb2, 512, 32);
    k_hgemm<2><<<dim3(16, 8), 256, 0, stream>>>(hb2, fw2, h0_b2, nullptr, hb1, 512, 32);
    k_hout<<<16, 256, 0, stream>>>(hb1, fow, out_b, out);
}

// Round 13
// 776.993 us; speedup vs baseline: 1.0555x; 1.0555x over previous
//
#include <hip/hip_runtime.h>
#include <math.h>

constexpr int N = 50000;     // nodes
constexpr int E = 100000;    // edges
constexpr int B = 256;       // graphs
constexpr int H = 64;
constexpr int DN = 110;

#define DEV __device__ __forceinline__

typedef __attribute__((ext_vector_type(8))) short short8;
typedef __attribute__((ext_vector_type(4))) float floatx4;

DEV float sigf(float x) { return 1.0f / (1.0f + expf(-x)); }

// bf16 round-to-nearest-even conversion (manual, header-type-free)
DEV short f2bf(float f) {
    unsigned u = __float_as_uint(f);
    unsigned r = (u + 0x7fffu + ((u >> 16) & 1u)) >> 16;
    return (short)r;
}
DEV float bf2f(short s) { return __uint_as_float(((unsigned)(unsigned short)s) << 16); }

// convert 8 contiguous floats -> hi/lo bf16 fragments
DEV void cvt8(const float* p, short8& hi, short8& lo) {
    float4 u0 = *(const float4*)p;
    float4 u1 = *(const float4*)(p + 4);
    float vv[8] = {u0.x, u0.y, u0.z, u0.w, u1.x, u1.y, u1.z, u1.w};
#pragma unroll
    for (int j = 0; j < 8; ++j) {
        short hb = f2bf(vv[j]);
        hi[j] = hb;
        lo[j] = f2bf(vv[j] - bf2f(hb));
    }
}

// ---------------- generic helpers ----------------
__global__ void k_izero(int* p, int n) {
    int i = blockIdx.x * 256 + threadIdx.x;
    if (i < n) p[i] = 0;
}

// ---------------- fused prep device helpers ----------------
DEV void d_transpose(const float* in, float* out, int R, int C, int idx) {
    int r = idx / C, c = idx % C;
    out[c * R + r] = in[idx];
}

DEV void d_prepB(const float* __restrict__ W, short* __restrict__ out,
                 int NT16, int ld, int trans, int ocap, int idx) {
    int lane = idx & 63;
    int t = idx >> 6;
    int ntile = t % NT16;
    int kt = t / NT16;
    int quad = lane >> 4, col = lane & 15;
    int o = ntile * 16 + col;
    short hi[8], lo[8];
#pragma unroll
    for (int j = 0; j < 8; ++j) {
        int k = kt * 32 + quad * 8 + j;
        float v = 0.0f;
        if (o < ocap) v = trans ? W[(size_t)o * ld + k] : W[(size_t)k * ld + o];
        short hb = f2bf(v);
        hi[j] = hb;
        lo[j] = f2bf(v - bf2f(hb));
    }
    short* dh = out + (((size_t)(t * 2 + 0) * 64 + lane) * 8);
    short* dl = out + (((size_t)(t * 2 + 1) * 64 + lane) * 8);
#pragma unroll
    for (int j = 0; j < 8; ++j) { dh[j] = hi[j]; dl[j] = lo[j]; }
}

DEV void d_prepW(const float* __restrict__ bond_W, const float* __restrict__ bond_b,
                 short* __restrict__ wf, int idx) {
    int lane = idx & 63;
    int t = idx >> 6;            // (kk*4+nt)*2+ks
    int ks = t & 1;
    int nt = (t >> 1) & 3;
    int kk = t >> 3;
    const float* S = (kk < 16) ? (bond_W + kk * 4096) : bond_b;
    int quad = lane >> 4, col = lane & 15;
    short hi[8], lo[8];
#pragma unroll
    for (int j = 0; j < 8; ++j) {
        int i = ks * 32 + quad * 8 + j;
        float v = S[i * 64 + nt * 16 + col];
        short hb = f2bf(v);
        hi[j] = hb;
        lo[j] = f2bf(v - bf2f(hb));
    }
    short* dh = wf + (((size_t)(t * 2 + 0) * 64 + lane) * 8);
    short* dl = wf + (((size_t)(t * 2 + 1) * 64 + lane) * 8);
#pragma unroll
    for (int j = 0; j < 8; ++j) { dh[j] = hi[j]; dl[j] = lo[j]; }
}

// fused start-of-graph prep: 4 LSTM transposes + bond prepW + 2 gru prepB + state zero
__launch_bounds__(256)
__global__ void k_prep0(const float* lWih0, const float* lWhh0, const float* lWih1, const float* lWhh1,
                        float* lW0T, float* lU0T, float* lW1T, float* lU1T,
                        const float* bond_W, const float* bond_b, short* wf,
                        const float* gru_Wih, const float* gru_Whh, short* fgI, short* fgH,
                        float* zreg) {
    int idx = blockIdx.x * 256 + threadIdx.x;
    if (idx < 131072) { d_transpose(lWih0, lW0T, 512, 256, idx); return; }
    idx -= 131072;
    if (idx < 65536) { d_transpose(lWhh0, lU0T, 512, 128, idx); return; }
    idx -= 65536;
    if (idx < 65536) { d_transpose(lWih1, lW1T, 512, 128, idx); return; }
    idx -= 65536;
    if (idx < 65536) { d_transpose(lWhh1, lU1T, 512, 128, idx); return; }
    idx -= 65536;
    if (idx < 8704) { d_prepW(bond_W, bond_b, wf, idx); return; }
    idx -= 8704;
    if (idx < 1536) { d_prepB(gru_Wih, fgI, 12, 64, 1, 192, idx); return; }
    idx -= 1536;
    if (idx < 1536) { d_prepB(gru_Whh, fgH, 12, 64, 1, 192, idx); return; }
    idx -= 1536;
    if (idx < 196608) { zreg[idx] = 0.0f; return; }
}
constexpr int PREP0_TOTAL = 131072 + 3 * 65536 + 8704 + 2 * 1536 + 196608;

// fused head prep: 4 prepB jobs (runs after MP loop; buffers alias ef_t)
__launch_bounds__(256)
__global__ void k_prephead(const float* sp_W, short* fsp, const float* h0_W1, short* fw1,
                           const float* h0_W2, short* fw2, const float* out_W, short* fow) {
    int idx = blockIdx.x * 256 + threadIdx.x;
    if (idx < 16384) { d_prepB(sp_W, fsp, 32, 512, 0, 512, idx); return; }
    idx -= 16384;
    if (idx < 32768) { d_prepB(h0_W1, fw1, 32, 512, 0, 512, idx); return; }
    idx -= 32768;
    if (idx < 32768) { d_prepB(h0_W2, fw2, 32, 512, 0, 512, idx); return; }
    idx -= 32768;
    if (idx < 4096) { d_prepB(out_W, fow, 4, 54, 0, 54, idx); return; }
}
constexpr int PREPH_TOTAL = 16384 + 2 * 32768 + 4096;

// ---------------- edge sort by dst (counting sort), one-time ----------------
__global__ void k_deg(const int* __restrict__ dst, int* __restrict__ deg) {
    int e = blockIdx.x * 256 + threadIdx.x;
    if (e < E) atomicAdd(&deg[dst[e]], 1);
}
__global__ void k_scan1(const int* __restrict__ deg, int* __restrict__ bsum) {
    __shared__ int s[256];
    int b = blockIdx.x, tid = threadIdx.x;
    int idx = b * 256 + tid;
    s[tid] = (idx < N) ? deg[idx] : 0;
    __syncthreads();
    for (int st = 128; st > 0; st >>= 1) {
        if (tid < st) s[tid] += s[tid + st];
        __syncthreads();
    }
    if (tid == 0) bsum[b] = s[0];
}
__global__ void k_scan2p(int* __restrict__ bsum, int nb) {
    __shared__ int s[256];
    int tid = threadIdx.x;
    int v = (tid < nb) ? bsum[tid] : 0;
    s[tid] = v;
    __syncthreads();
    for (int off = 1; off < 256; off <<= 1) {
        int t = (tid >= off) ? s[tid - off] : 0;
        __syncthreads();
        s[tid] += t;
        __syncthreads();
    }
    if (tid < nb) bsum[tid] = s[tid] - v;   // exclusive
}
__global__ void k_scan3(const int* __restrict__ deg, const int* __restrict__ bsum,
                        int* __restrict__ cursor, int* __restrict__ roff) {
    __shared__ int s[256];
    int b = blockIdx.x, tid = threadIdx.x;
    int idx = b * 256 + tid;
    int v = (idx < N) ? deg[idx] : 0;
    s[tid] = v;
    __syncthreads();
    for (int off = 1; off < 256; off <<= 1) {
        int t = (tid >= off) ? s[tid - off] : 0;
        __syncthreads();
        s[tid] += t;
        __syncthreads();
    }
    if (idx < N) {
        int start = bsum[b] + s[tid] - v;
        cursor[idx] = start;
        roff[idx] = start;
    }
    if (idx == 0) roff[N] = E;
}
__global__ void k_scat(const int* __restrict__ src, const int* __restrict__ dst,
                       int* __restrict__ cursor, int* __restrict__ srcp,
                       int* __restrict__ epos) {
    int e = blockIdx.x * 256 + threadIdx.x;
    if (e >= E) return;
    int d = dst[e];
    int pos = atomicAdd(&cursor[d], 1);
    srcp[pos] = src[e];
    epos[e] = pos;
}

// ---------------- projection: v = relu(na @ W + b); x = v (fp32); hs = split(v) ----------------
__launch_bounds__(256)
__global__ void k_proj(const float* __restrict__ na, const float* __restrict__ W,
                       const float* __restrict__ b, float* __restrict__ x,
                       short* __restrict__ hs) {
    __shared__ float Ws[DN * 64];
    __shared__ float as[16][112];
    int tid = threadIdx.x;
    for (int i = tid; i < DN * 64; i += 256) Ws[i] = W[i];
    int n0 = blockIdx.x * 16;
    for (int i = tid; i < 16 * DN; i += 256) {
        int nn = i / DN, ii = i % DN;
        as[nn][ii] = na[(n0 + nn) * DN + ii];
    }
    __syncthreads();
    int o = tid & 63, ng = tid >> 6;
    float bo = b[o];
    for (int j = 0; j < 4; ++j) {
        int nn = ng * 4 + j;
        float acc = bo;
#pragma unroll 10
        for (int i = 0; i < DN; ++i) acc += as[nn][i] * Ws[i * 64 + o];
        float v = fmaxf(acc, 0.0f);
        int n = n0 + nn;
        x[(size_t)n * 64 + o] = v;
        short hb = f2bf(v);
        hs[(size_t)n * 128 + o] = hb;
        hs[(size_t)n * 128 + 64 + o] = f2bf(v - bf2f(hb));
    }
}

// ---------------- edge features -> ef_t[kk][pos] in dst-sorted order ----------------
__global__ void k_efeat2(const float* __restrict__ ea, const float* __restrict__ el,
                         const float* __restrict__ centers, const float* __restrict__ beta,
                         const int* __restrict__ epos, float* __restrict__ ef_t) {
    int e = blockIdx.x * 256 + threadIdx.x;
    if (e >= E) return;
    int pos = epos[e];
    float L = el[e];
#pragma unroll
    for (int j = 0; j < 8; ++j) ef_t[j * E + pos] = ea[e * 8 + j];
#pragma unroll
    for (int j = 0; j < 8; ++j) {
        float d = L - centers[j];
        ef_t[(8 + j) * E + pos] = expf(-beta[j] * d * d);
    }
    ef_t[16 * E + pos] = 1.0f;
}

// ---------------- message GEMM, M=64, 3-deep B prefetch, plain stores ----------------
__launch_bounds__(256)
__global__ void k_msg8(const short* __restrict__ hs, const float* __restrict__ ef_t,
                       const short* __restrict__ wf, const int* __restrict__ srcp,
                       float* __restrict__ m) {
    __shared__ float efs[17 * 64];   // [kk][e_local]
    __shared__ int srcs[64];

    int tid = threadIdx.x;
    int e0 = blockIdx.x * 64;
    int lane = tid & 63;
    int nt = tid >> 6;
    int quad = lane >> 4, col = lane & 15;

    if (tid < 64) {
        int eg = e0 + tid;
        srcs[tid] = (eg < E) ? srcp[eg] : 0;
    }
    for (int i = tid; i < 17 * 64; i += 256) {
        int kk = i >> 6, e = i & 63;
        int eg = e0 + e;
        efs[i] = (eg < E) ? ef_t[(size_t)kk * E + eg] : 0.0f;
    }
    __syncthreads();

    // A fragments: direct pre-split loads (hi at +0..63, lo at +64..127 per node row)
    short8 Ah[4][2], Al[4][2];
#pragma unroll
    for (int mt = 0; mt < 4; ++mt) {
        int s = srcs[mt * 16 + col];
        const short* hp = hs + (size_t)s * 128 + quad * 8;
#pragma unroll
        for (int ks = 0; ks < 2; ++ks) {
            Ah[mt][ks] = *(const short8*)(hp + ks * 32);
            Al[mt][ks] = *(const short8*)(hp + 64 + ks * 32);
        }
    }

    const short8* Wf = (const short8*)wf;
    float C[4][4] = {};

#define LOADB(d0, d1, d2, d3, KK)                      \
    {                                                  \
        int tb_ = ((KK) * 4 + nt) * 2;                 \
        d0 = Wf[((tb_ + 0) * 2 + 0) * 64 + lane];      \
        d1 = Wf[((tb_ + 1) * 2 + 0) * 64 + lane];      \
        d2 = Wf[((tb_ + 0) * 2 + 1) * 64 + lane];      \
        d3 = Wf[((tb_ + 1) * 2 + 1) * 64 + lane];      \
    }

    // 3-deep software pipeline: hold kk, kk+1, kk+2; prefetch kk+3 each iteration
    short8 c0, c1, c2, c3, n0_, n1_, n2_, n3_, q0, q1, q2, q3;
    LOADB(c0, c1, c2, c3, 0);
    LOADB(n0_, n1_, n2_, n3_, 1);
    LOADB(q0, q1, q2, q3, 2);

#pragma unroll 1
    for (int kk = 0; kk < 17; ++kk) {
        int kn = kk + 3;
        if (kn > 16) kn = 16;
        short8 p0, p1, p2, p3;
        LOADB(p0, p1, p2, p3, kn);

#pragma unroll
        for (int mt = 0; mt < 4; ++mt) {
            floatx4 T = {0.0f, 0.0f, 0.0f, 0.0f};
            T = __builtin_amdgcn_mfma_f32_16x16x32_bf16(Ah[mt][0], c0, T, 0, 0, 0);
            T = __builtin_amdgcn_mfma_f32_16x16x32_bf16(Ah[mt][1], c1, T, 0, 0, 0);
            T = __builtin_amdgcn_mfma_f32_16x16x32_bf16(Al[mt][0], c0, T, 0, 0, 0);
            T = __builtin_amdgcn_mfma_f32_16x16x32_bf16(Al[mt][1], c1, T, 0, 0, 0);
            T = __builtin_amdgcn_mfma_f32_16x16x32_bf16(Ah[mt][0], c2, T, 0, 0, 0);
            T = __builtin_amdgcn_mfma_f32_16x16x32_bf16(Ah[mt][1], c3, T, 0, 0, 0);
            float4 ef = *(const float4*)&efs[kk * 64 + mt * 16 + quad * 4];
            C[mt][0] += ef.x * T[0];
            C[mt][1] += ef.y * T[1];
            C[mt][2] += ef.z * T[2];
            C[mt][3] += ef.w * T[3];
        }
        c0 = n0_; c1 = n1_; c2 = n2_; c3 = n3_;
        n0_ = q0; n1_ = q1; n2_ = q2; n3_ = q3;
        q0 = p0; q1 = p1; q2 = p2; q3 = p3;
    }
#undef LOADB

    int o = nt * 16 + col;
#pragma unroll
    for (int mt = 0; mt < 4; ++mt) {
#pragma unroll
        for (int r = 0; r < 4; ++r) {
            int eg = e0 + mt * 16 + quad * 4 + r;
            if (eg < E) m[(size_t)eg * 64 + o] = C[mt][r];
        }
    }
}

// ---------------- GRU step: CSR gather + conv_b + relu -> split-bf16 MFMA; h stored split in hs ----------------
__launch_bounds__(256)
__global__ void k_gru3(const float* __restrict__ m, const int* __restrict__ roff,
                       const float* __restrict__ conv_b, short* __restrict__ hs,
                       const short* __restrict__ fI, const short* __restrict__ fH,
                       const float* __restrict__ bih, const float* __restrict__ bhh) {
    int tid = threadIdx.x, lane = tid & 63, nt = tid >> 6;
    int quad = lane >> 4, col = lane & 15;
    int n0 = blockIdx.x * 32;

    short8 Gh[2][2], Gl[2][2], Hh[2][2], Hl[2][2];
#pragma unroll
    for (int mt = 0; mt < 2; ++mt) {
        int node = n0 + mt * 16 + col;
        bool ok = node < N;
        int nc = ok ? node : (N - 1);
        int rs = roff[nc];
        int re = ok ? roff[nc + 1] : rs;
        float acc[2][8];
#pragma unroll
        for (int ks = 0; ks < 2; ++ks) {
            const float* cb = conv_b + ks * 32 + quad * 8;
#pragma unroll
            for (int j = 0; j < 8; ++j) acc[ks][j] = cb[j];
        }
        for (int r = rs; r < re; ++r) {
            const float* mp = m + (size_t)r * 64 + quad * 8;
            float4 a0 = *(const float4*)mp;
            float4 a1 = *(const float4*)(mp + 4);
            float4 b0 = *(const float4*)(mp + 32);
            float4 b1 = *(const float4*)(mp + 36);
            acc[0][0] += a0.x; acc[0][1] += a0.y; acc[0][2] += a0.z; acc[0][3] += a0.w;
            acc[0][4] += a1.x; acc[0][5] += a1.y; acc[0][6] += a1.z; acc[0][7] += a1.w;
            acc[1][0] += b0.x; acc[1][1] += b0.y; acc[1][2] += b0.z; acc[1][3] += b0.w;
            acc[1][4] += b1.x; acc[1][5] += b1.y; acc[1][6] += b1.z; acc[1][7] += b1.w;
        }
        const short* hp = hs + (size_t)nc * 128 + quad * 8;
#pragma unroll
        for (int ks = 0; ks < 2; ++ks) {
            short8 hh8 = *(const short8*)(hp + ks * 32);
            short8 hl8 = *(const short8*)(hp + 64 + ks * 32);
            Hh[mt][ks] = hh8;
            Hl[mt][ks] = hl8;
#pragma unroll
            for (int j = 0; j < 8; ++j) {
                float g = ok ? fmaxf(acc[ks][j], 0.0f) : 0.0f;
                short gb = f2bf(g);
                Gh[mt][ks][j] = gb;
                Gl[mt][ks][j] = f2bf(g - bf2f(gb));
            }
        }
        if (!ok) {
#pragma unroll
            for (int ks = 0; ks < 2; ++ks) {
                Hh[mt][ks] = short8{0,0,0,0,0,0,0,0};
                Hl[mt][ks] = short8{0,0,0,0,0,0,0,0};
            }
        }
    }
    __syncthreads();  // all hs reads complete before any wave writes hs below

    const short8* FI = (const short8*)fI;
    const short8* FH = (const short8*)fH;
    floatx4 aI[2][3] = {}, aH[2][3] = {};
#pragma unroll
    for (int ks = 0; ks < 2; ++ks) {
        short8 bIh[3], bIl[3], bHh[3], bHl[3];
#pragma unroll
        for (int g = 0; g < 3; ++g) {
            int t = ks * 12 + g * 4 + nt;   // NT16 = 12 (Nout=192)
            bIh[g] = FI[(t * 2 + 0) * 64 + lane];
            bIl[g] = FI[(t * 2 + 1) * 64 + lane];
            bHh[g] = FH[(t * 2 + 0) * 64 + lane];
            bHl[g] = FH[(t * 2 + 1) * 64 + lane];
        }
#pragma unroll
        for (int mt = 0; mt < 2; ++mt) {
#pragma unroll
            for (int g = 0; g < 3; ++g) {
                aI[mt][g] = __builtin_amdgcn_mfma_f32_16x16x32_bf16(Gh[mt][ks], bIh[g], aI[mt][g], 0, 0, 0);
                aI[mt][g] = __builtin_amdgcn_mfma_f32_16x16x32_bf16(Gl[mt][ks], bIh[g], aI[mt][g], 0, 0, 0);
                aI[mt][g] = __builtin_amdgcn_mfma_f32_16x16x32_bf16(Gh[mt][ks], bIl[g], aI[mt][g], 0, 0, 0);
                aH[mt][g] = __builtin_amdgcn_mfma_f32_16x16x32_bf16(Hh[mt][ks], bHh[g], aH[mt][g], 0, 0, 0);
                aH[mt][g] = __builtin_amdgcn_mfma_f32_16x16x32_bf16(Hl[mt][ks], bHh[g], aH[mt][g], 0, 0, 0);
                aH[mt][g] = __builtin_amdgcn_mfma_f32_16x16x32_bf16(Hh[mt][ks], bHl[g], aH[mt][g], 0, 0, 0);
            }
        }
    }

    int o = nt * 16 + col;
    float br = bih[o], bz = bih[64 + o], bn = bih[128 + o];
    float cr = bhh[o], cz = bhh[64 + o], cn = bhh[128 + o];
#pragma unroll
    for (int mt = 0; mt < 2; ++mt) {
#pragma unroll
        for (int r = 0; r < 4; ++r) {
            int node = n0 + mt * 16 + quad * 4 + r;
            if (node >= N) continue;
            float rg = sigf(aI[mt][0][r] + br + aH[mt][0][r] + cr);
            float z  = sigf(aI[mt][1][r] + bz + aH[mt][1][r] + cz);
            float ng = tanhf(aI[mt][2][r] + bn + rg * (aH[mt][2][r] + cn));
            size_t hb_ = (size_t)node * 128 + o;
            float hold = bf2f(hs[hb_]) + bf2f(hs[hb_ + 64]);
            float hn = (1.0f - z) * ng + z * hold;
            short hi = f2bf(hn);
            hs[hb_] = hi;
            hs[hb_ + 64] = f2bf(hn - bf2f(hi));
        }
    }
}

// ---------------- graph bounds: sorted node_graph -> boundary detection, no atomics ----------------
__global__ void k_bounds2(const int* __restrict__ ng, int* __restrict__ gs, int* __restrict__ ge) {
    int n = blockIdx.x * 256 + threadIdx.x;
    if (n >= N) return;
    int g = ng[n];
    int gp = (n == 0) ? -1 : ng[n - 1];
    if (g != gp) {
        gs[g] = n;
        if (n > 0) ge[gp] = n;
        for (int q = gp + 1; q < g; ++q) { gs[q] = 0; ge[q] = 0; }
    }
    if (n == N - 1) {
        ge[g] = N;
        for (int q = g + 1; q < B; ++q) { gs[q] = 0; ge[q] = 0; }
    }
}

// ---------------- fused Set2Set iteration: 2-layer LSTM + online-softmax attention (4x unrolled) ----------------
__launch_bounds__(256)
__global__ void k_s2s(float* __restrict__ h0, float* __restrict__ c0,
                      float* __restrict__ h1, float* __restrict__ c1,
                      float* __restrict__ q_star,
                      const float* __restrict__ W0T, const float* __restrict__ U0T,
                      const float* __restrict__ b0i, const float* __restrict__ b0h,
                      const float* __restrict__ W1T, const float* __restrict__ U1T,
                      const float* __restrict__ b1i, const float* __restrict__ b1h,
                      const short* __restrict__ hs, const float* __restrict__ x,
                      const int* __restrict__ gs, const int* __restrict__ ge) {
    __shared__ float xb[256], hb[128], gb[512], h0n[128], qv[128];
    __shared__ float mrg[4][2][64];
    __shared__ float ml[4][2];
    int g = blockIdx.x, tid = threadIdx.x;
    xb[tid] = q_star[g * 256 + tid];
    if (tid < 128) hb[tid] = h0[g * 128 + tid];
    __syncthreads();
    // ---- LSTM layer 0 ----
    float g0 = b0i[tid] + b0h[tid];
    float g1 = b0i[tid + 256] + b0h[tid + 256];
    for (int i = 0; i < 256; ++i) {
        float xx = xb[i];
        g0 += xx * W0T[i * 512 + tid];
        g1 += xx * W0T[i * 512 + tid + 256];
    }
    for (int i = 0; i < 128; ++i) {
        float hh = hb[i];
        g0 += hh * U0T[i * 512 + tid];
        g1 += hh * U0T[i * 512 + tid + 256];
    }
    gb[tid] = g0; gb[tid + 256] = g1;
    __syncthreads();
    if (tid < 128) {
        float ii = gb[tid], ff = gb[128 + tid], gg = gb[256 + tid], oo = gb[384 + tid];
        float c = sigf(ff) * c0[g * 128 + tid] + sigf(ii) * tanhf(gg);
        float hn = sigf(oo) * tanhf(c);
        c0[g * 128 + tid] = c; h0[g * 128 + tid] = hn; h0n[tid] = hn;
        hb[tid] = h1[g * 128 + tid];
    }
    __syncthreads();
    // ---- LSTM layer 1 ----
    float ga = b1i[tid] + b1h[tid];
    float gbv = b1i[tid + 256] + b1h[tid + 256];
    for (int i = 0; i < 128; ++i) {
        float xx = h0n[i], hh = hb[i];
        ga  += xx * W1T[i * 512 + tid]       + hh * U1T[i * 512 + tid];
        gbv += xx * W1T[i * 512 + tid + 256] + hh * U1T[i * 512 + tid + 256];
    }
    gb[tid] = ga; gb[tid + 256] = gbv;
    __syncthreads();
    if (tid < 128) {
        float ii = gb[tid], ff = gb[128 + tid], gg = gb[256 + tid], oo = gb[384 + tid];
        float c = sigf(ff) * c1[g * 128 + tid] + sigf(ii) * tanhf(gg);
        float hn = sigf(oo) * tanhf(c);
        c1[g * 128 + tid] = c; h1[g * 128 + tid] = hn;
        q_star[g * 256 + tid] = hn;   // q half
        qv[tid] = hn;
    }
    __syncthreads();
    // ---- attention with online softmax, 4 nodes per iteration (batched loads) ----
    int s0v = gs[g], s1v = ge[g];
    int lane = tid & 63, grp = tid >> 6;
    float qh = qv[lane], qx = qv[64 + lane];
    float mM = -INFINITY, lL = 0.0f, nh = 0.0f, nx = 0.0f;
    for (int n = s0v + grp; n < s1v; n += 16) {
        float hv[4], xv[4], e[4];
#pragma unroll
        for (int j = 0; j < 4; ++j) {
            int nj = n + 4 * j;
            int nc = (nj < s1v) ? nj : n;   // clamp: n itself is always valid
            hv[j] = bf2f(hs[(size_t)nc * 128 + lane]) + bf2f(hs[(size_t)nc * 128 + 64 + lane]);
            xv[j] = x[(size_t)nc * 64 + lane];
            e[j] = hv[j] * qh + xv[j] * qx;
        }
#pragma unroll
        for (int off = 32; off; off >>= 1) {
#pragma unroll
            for (int j = 0; j < 4; ++j) e[j] += __shfl_xor(e[j], off, 64);
        }
#pragma unroll
        for (int j = 0; j < 4; ++j)
            if (n + 4 * j >= s1v) e[j] = -INFINITY;
        float mb = fmaxf(fmaxf(e[0], e[1]), fmaxf(e[2], e[3]));
        float mn = fmaxf(mM, mb);
        float sc = expf(mM - mn);
        float w0 = expf(e[0] - mn), w1 = expf(e[1] - mn);
        float w2 = expf(e[2] - mn), w3 = expf(e[3] - mn);
        lL = lL * sc + ((w0 + w1) + (w2 + w3));
        nh = nh * sc + ((w0 * hv[0] + w1 * hv[1]) + (w2 * hv[2] + w3 * hv[3]));
        nx = nx * sc + ((w0 * xv[0] + w1 * xv[1]) + (w2 * xv[2] + w3 * xv[3]));
        mM = mn;
    }
    mrg[grp][0][lane] = nh;
    mrg[grp][1][lane] = nx;
    if (lane == 0) { ml[grp][0] = mM; ml[grp][1] = lL; }
    __syncthreads();
    if (tid < 128) {
        int half = tid >> 6, dl = tid & 63;
        float M = -INFINITY;
#pragma unroll
        for (int i = 0; i < 4; ++i) M = fmaxf(M, ml[i][0]);
        float L = 0.0f, NUM = 0.0f;
#pragma unroll
        for (int i = 0; i < 4; ++i) {
            float sc = expf(ml[i][0] - M);
            L += ml[i][1] * sc;
            NUM += mrg[i][half][dl] * sc;
        }
        q_star[g * 256 + 128 + tid] = (s1v > s0v) ? NUM / L : 0.0f;
    }
}

// ---------------- head GEMM layer: C = act(A @ W + b), tiled MFMA ----------------
template<int MODE>
__launch_bounds__(256)
__global__ void k_hgemm(const float* __restrict__ A, const short* __restrict__ Bf,
                        const float* __restrict__ bias, const float* __restrict__ pa,
                        float* __restrict__ Cout, int K, int NT16) {
    int tid = threadIdx.x, lane = tid & 63, nt = tid >> 6;
    int quad = lane >> 4, col = lane & 15;
    int s0 = blockIdx.x * 16;
    int ntile = blockIdx.y * 4 + nt;
    int NoutTot = NT16 * 16;
    const short8* F = (const short8*)Bf;
    floatx4 T = {0.0f, 0.0f, 0.0f, 0.0f};
    const float* ap = A + (size_t)(s0 + col) * K + quad * 8;
    int KT = K >> 5;
#pragma unroll 4
    for (int kt = 0; kt < KT; ++kt) {
        short8 ah, al;
        cvt8(ap + kt * 32, ah, al);
        int t = kt * NT16 + ntile;
        short8 bh = F[(t * 2 + 0) * 64 + lane];
        short8 bl = F[(t * 2 + 1) * 64 + lane];
        T = __builtin_amdgcn_mfma_f32_16x16x32_bf16(ah, bh, T, 0, 0, 0);
        T = __builtin_amdgcn_mfma_f32_16x16x32_bf16(al, bh, T, 0, 0, 0);
        T = __builtin_amdgcn_mfma_f32_16x16x32_bf16(ah, bl, T, 0, 0, 0);
    }
    int o = ntile * 16 + col;
    float b = bias[o];
    float a = (MODE == 0) ? pa[0] : 0.0f;
#pragma unroll
    for (int r = 0; r < 4; ++r) {
        float v = T[r] + b;
        if (MODE == 0) v = (v >= 0.0f) ? v : a * v;
        if (MODE == 1) v = fmaxf(v, 0.0f);
        if (MODE == 2) v = tanhf(v);
        Cout[(size_t)(s0 + quad * 4 + r) * NoutTot + o] = v;
    }
}

// ---------------- head output layer + softmax ----------------
__launch_bounds__(256)
__global__ void k_hout(const float* __restrict__ A, const short* __restrict__ Bf,
                       const float* __restrict__ ob, float* __restrict__ out) {
    __shared__ float sm[16][64];
    __shared__ float smax[16], sinv[16];
    int tid = threadIdx.x, lane = tid & 63, nt = tid >> 6;
    int quad = lane >> 4, col = lane & 15;
    int s0 = blockIdx.x * 16;
    const short8* F = (const short8*)Bf;
    floatx4 T = {0.0f, 0.0f, 0.0f, 0.0f};
    const float* ap = A + (size_t)(s0 + col) * 512 + quad * 8;
#pragma unroll 4
    for (int kt = 0; kt < 16; ++kt) {
        short8 ah, al;
        cvt8(ap + kt * 32, ah, al);
        int t = kt * 4 + nt;
        short8 bh = F[(t * 2 + 0) * 64 + lane];
        short8 bl = F[(t * 2 + 1) * 64 + lane];
        T = __builtin_amdgcn_mfma_f32_16x16x32_bf16(ah, bh, T, 0, 0, 0);
        T = __builtin_amdgcn_mfma_f32_16x16x32_bf16(al, bh, T, 0, 0, 0);
        T = __builtin_amdgcn_mfma_f32_16x16x32_bf16(ah, bl, T, 0, 0, 0);
    }
    int o = nt * 16 + col;
    float b = (o < 54) ? ob[o] : 0.0f;
#pragma unroll
    for (int r = 0; r < 4; ++r)
        sm[quad * 4 + r][o] = (o < 54) ? (T[r] + b) : -1e30f;
    __syncthreads();
    if (tid < 16) {
        float m = -INFINITY;
        for (int j = 0; j < 54; ++j) m = fmaxf(m, sm[tid][j]);
        float s = 0.0f;
        for (int j = 0; j < 54; ++j) s += expf(sm[tid][j] - m);
        smax[tid] = m;
        sinv[tid] = 1.0f / s;
    }
    __syncthreads();
    for (int idx = tid; idx < 16 * 54; idx += 256) {
        int srow = idx / 54, oo = idx % 54;
        out[(size_t)(s0 + srow) * 54 + oo] = expf(sm[srow][oo] - smax[srow]) * sinv[srow];
    }
}

// ---------------- driver ----------------
extern "C" void kernel_launch(void* const* d_in, const int* in_sizes, int n_in,
                              void* d_out, int out_size, void* d_ws, size_t ws_size,
                              hipStream_t stream) {
    const float* node_attr = (const float*)d_in[0];
    const float* edge_attr = (const float*)d_in[1];
    const float* edge_len  = (const float*)d_in[2];
    const int*   src       = (const int*)d_in[3];
    const int*   dst       = (const int*)d_in[4];
    const int*   node_grph = (const int*)d_in[5];
    const float* proj_W    = (const float*)d_in[6];
    const float* proj_b    = (const float*)d_in[7];
    const float* centers   = (const float*)d_in[8];
    const float* beta      = (const float*)d_in[9];
    const float* bond_W    = (const float*)d_in[10];
    const float* bond_b    = (const float*)d_in[11];
    const float* conv_b    = (const float*)d_in[12];
    const float* gru_Wih   = (const float*)d_in[13];
    const float* gru_Whh   = (const float*)d_in[14];
    const float* gru_bih   = (const float*)d_in[15];
    const float* gru_bhh   = (const float*)d_in[16];
    const float* lWih0     = (const float*)d_in[17];
    const float* lWhh0     = (const float*)d_in[18];
    const float* lbih0     = (const float*)d_in[19];
    const float* lbhh0     = (const float*)d_in[20];
    const float* lWih1     = (const float*)d_in[21];
    const float* lWhh1     = (const float*)d_in[22];
    const float* lbih1     = (const float*)d_in[23];
    const float* lbhh1     = (const float*)d_in[24];
    const float* sp_W      = (const float*)d_in[25];
    const float* sp_b      = (const float*)d_in[26];
    const float* prelu_a   = (const float*)d_in[27];
    const float* h0_W1     = (const float*)d_in[28];
    const float* h0_b1     = (const float*)d_in[29];
    const float* h0_W2     = (const float*)d_in[30];
    const float* h0_b2     = (const float*)d_in[31];
    const float* out_W     = (const float*)d_in[32];
    const float* out_b     = (const float*)d_in[33];
    float* out = (float*)d_out;

    float* ws = (float*)d_ws;
    size_t off = 0;
    float* x      = ws + off; off += (size_t)N * 64;
    float* hsf    = ws + off; off += (size_t)N * 64;   // N x 128 shorts (hi|lo per node)
    float* ef_t   = ws + off; off += (size_t)E * 17;   // reused by head after MP loop
    float* m      = ws + off; off += (size_t)E * 64;   // per-edge messages (dst-sorted)
    float* wfrag  = ws + off; off += 17 * 16 * 64 * 8 / 2;
    float* fgI    = ws + off; off += 2 * 64 * 192 / 2;
    float* fgH    = ws + off; off += 2 * 64 * 192 / 2;
    float* lW0T   = ws + off; off += 256 * 512;
    float* lU0T   = ws + off; off += 128 * 512;
    float* lW1T   = ws + off; off += 128 * 512;
    float* lU1T   = ws + off; off += 128 * 512;
    float* h0     = ws + off; off += B * 128;
    float* c0     = ws + off; off += B * 128;
    float* h1     = ws + off; off += B * 128;
    float* c1     = ws + off; off += B * 128;
    float* q_star = ws + off; off += B * 256;
    int* gs       = (int*)(ws + off); off += B;
    int* ge       = (int*)(ws + off); off += B;
    int* deg      = (int*)(ws + off); off += N;
    int* cursor   = (int*)(ws + off); off += N;
    int* roff     = (int*)(ws + off); off += N + 1;
    int* bsum     = (int*)(ws + off); off += 256;
    int* srcp     = (int*)(ws + off); off += E;
    int* epos     = (int*)(ws + off); off += E;

    short* hs = (short*)hsf;

    // head buffers alias the ef_t region (dead after the MP loop)
    short* fsp = (short*)ef_t;
    short* fw1 = (short*)(ef_t + 131072);
    short* fw2 = (short*)(ef_t + 131072 + 262144);
    short* fow = (short*)(ef_t + 131072 + 2 * 262144);
    float* hb1 = ef_t + 131072 + 2 * 262144 + 32768;
    float* hb2 = hb1 + 131072;

    constexpr int NB = (N + 255) / 256;   // 196

    // ---- one-time: counting sort of edges by dst + CSR offsets ----
    k_izero<<<NB, 256, 0, stream>>>(deg, N);
    k_deg<<<(E + 255) / 256, 256, 0, stream>>>(dst, deg);
    k_scan1<<<NB, 256, 0, stream>>>(deg, bsum);
    k_scan2p<<<1, 256, 0, stream>>>(bsum, NB);
    k_scan3<<<NB, 256, 0, stream>>>(deg, bsum, cursor, roff);
    k_scat<<<(E + 255) / 256, 256, 0, stream>>>(src, dst, cursor, srcp, epos);

    // fused prep: LSTM transposes + bond/gru fragment prep + LSTM-state zero (h0..q_star contiguous)
    k_prep0<<<(PREP0_TOTAL + 255) / 256, 256, 0, stream>>>(
        lWih0, lWhh0, lWih1, lWhh1, lW0T, lU0T, lW1T, lU1T,
        bond_W, bond_b, (short*)wfrag, gru_Wih, gru_Whh, (short*)fgI, (short*)fgH, h0);

    k_proj<<<N / 16, 256, 0, stream>>>(node_attr, proj_W, proj_b, x, hs);
    k_efeat2<<<(E + 255) / 256, 256, 0, stream>>>(edge_attr, edge_len, centers, beta, epos, ef_t);

    k_bounds2<<<(N + 255) / 256, 256, 0, stream>>>(node_grph, gs, ge);

    for (int step = 0; step < 4; ++step) {
        k_msg8<<<(E + 63) / 64, 256, 0, stream>>>(hs, ef_t, (const short*)wfrag, srcp, m);
        k_gru3<<<(N + 31) / 32, 256, 0, stream>>>(m, roff, conv_b, hs,
                                                  (const short*)fgI, (const short*)fgH,
                                                  gru_bih, gru_bhh);
    }

    // fused head fragment prep (ef_t region now dead)
    k_prephead<<<(PREPH_TOTAL + 255) / 256, 256, 0, stream>>>(
        sp_W, fsp, h0_W1, fw1, h0_W2, fw2, out_W, fow);

    for (int it = 0; it < 3; ++it) {
        k_s2s<<<B, 256, 0, stream>>>(h0, c0, h1, c1, q_star,
                                     lW0T, lU0T, lbih0, lbhh0,
                                     lW1T, lU1T, lbih1, lbhh1,
                                     hs, x, gs, ge);
    }

    // head: 3 MFMA GEMM layers + fused output/softmax
    k_hgemm<0><<<dim3(16, 8), 256, 0, stream>>>(q_star, fsp, sp_b, prelu_a, hb1, 256, 32);
    k_hgemm<1><<<dim3(16, 8), 256, 0, stream>>>(hb1, fw1, h0_b1, nullptr, hb2, 512, 32);
    k_hgemm<2><<<dim3(16, 8), 256, 0, stream>>>(hb2, fw2, h0_b2, nullptr, hb1, 512, 32);
    k_hout<<<16, 256, 0, stream>>>(hb1, fow, out_b, out);
}